// Round 1
// baseline (10041.584 us; speedup 1.0000x reference)
//
#include <hip/hip_runtime.h>

// DeepLSTM on MI355X — persistent kernel (plain launch, 208 blocks, co-resident),
// relaxed-atomic grid barrier (no cache maintenance), weights persistent in VGPR/AGPR.
// ROUND 6: K-loop software pipeline, depth-4 register relay, raw s_barrier per chunk.
// ROUND 7: h1/h2 reads converted from 8B agent-scope atomic loads (LLC request-rate
// bound: ~5.7M tiny requests/step ≈ 18us/step) to plain cached uint4 loads that hit
// per-XCD L2 and are shared across co-XCD blocks. Coherence: h stores remain agent
// atomics (write-through to LLC) + syncthreads drain before barrier publish; every
// block executes an acquire fence (buffer_inv, L1+L2) immediately after each grid
// barrier, before touching the freshly published h slot. During a round the slot
// being written is read by nobody (parity scheme), so no stale line can be
// re-introduced between a block's fence and its reads.

typedef __attribute__((ext_vector_type(8))) short short8;
typedef __attribute__((ext_vector_type(16))) float f32x16;
typedef __attribute__((ext_vector_type(4))) float f32x4;

#define Tn 256
#define In 256
#define Hn 1024
#define On 256
#define SP 136            // LDS act row stride (elems): 272B rows, 16B-aligned
#define NL1 64
#define NL2 128
#define NY  16
#define NBLK (NL1 + NL2 + NY)   // 208
#define CHUNK_B 17408     // 64*SP*2 bytes per LDS act chunk (128 K-cols)
#define SMEM_SZ 55808     // 2*CHUNK_B + 16896 (gate xchg) + 4096 (cell state)
#define BHe 65536

// d_ws layout
#define WS_WIH1 0
#define WS_WHH1 2097152
#define WS_WIH2 10485760
#define WS_WHH2 20971520
#define WS_WL   29360128
#define WS_X    30015488
#define WS_H1   38404096
#define WS_H2   38666240
#define WS_ARR  38928384

// s_waitcnt lgkmcnt(0), vmcnt/expcnt unconstrained (gfx9 encoding)
#define WAIT_LGKM0() __builtin_amdgcn_s_waitcnt(0xC07F)
#define RAW_BARRIER() do { \
    WAIT_LGKM0(); \
    __builtin_amdgcn_sched_barrier(0); \
    __builtin_amdgcn_s_barrier(); \
    __builtin_amdgcn_sched_barrier(0); \
  } while (0)

// Acquire fence at agent scope: emits buffer_inv (L1 + L2 invalidate) so plain
// loads of h1buf/h2buf observe remote XCDs' write-through atomic stores.
#define ACQ_FENCE() __builtin_amdgcn_fence(__ATOMIC_ACQUIRE, "agent")

static __device__ __forceinline__ unsigned short f2b(float f) {
  union { float f; unsigned int i; } v; v.f = f;
  unsigned int u = v.i;
  return (unsigned short)((u + 0x7FFFu + ((u >> 16) & 1u)) >> 16);  // RNE
}
static __device__ __forceinline__ float sigm(float x) { return 1.0f / (1.0f + __expf(-x)); }
static __device__ __forceinline__ float tanhf_(float x) {
  float ax = fabsf(x);
  float e = __expf(-2.0f * ax);
  return copysignf((1.0f - e) / (1.0f + e), x);
}
static __device__ __forceinline__ void st32a(void* p, unsigned int v) {
  __hip_atomic_store((unsigned int*)p, v, __ATOMIC_RELAXED, __HIP_MEMORY_SCOPE_AGENT);
}
static __device__ __forceinline__ void st64a(void* p, unsigned long long v) {
  __hip_atomic_store((unsigned long long*)p, v, __ATOMIC_RELAXED, __HIP_MEMORY_SCOPE_AGENT);
}

static __device__ __forceinline__ void grid_barrier(int* arrive, int bid, int tid,
                                                    int lane, int tgt) {
  __syncthreads();   // full drain (vmcnt0): h-stores visible before publish
  if (tid == 0)
    __hip_atomic_store(&arrive[bid], tgt, __ATOMIC_RELAXED, __HIP_MEMORY_SCOPE_AGENT);
  if (tid < 64) {
    bool done = false;
    while (!done) {
      bool ok = true;
      #pragma unroll
      for (int j = 0; j < 4; ++j) {
        int idx = lane + j * 64;
        if (idx < NBLK) {
          int v = __hip_atomic_load(&arrive[idx], __ATOMIC_RELAXED, __HIP_MEMORY_SCOPE_AGENT);
          ok = ok && (v >= tgt);
        }
      }
      done = __all(ok);
      if (!done) __builtin_amdgcn_s_sleep(1);
    }
  }
  __syncthreads();
}

__global__ void __launch_bounds__(256) cvt_bf16(const float* __restrict__ src,
                                                unsigned short* __restrict__ dst, int n4) {
  int i = blockIdx.x * blockDim.x + threadIdx.x;
  if (i >= n4) return;
  float4 v = ((const float4*)src)[i];
  ushort4 o;
  o.x = f2b(v.x); o.y = f2b(v.y); o.z = f2b(v.z); o.w = f2b(v.w);
  ((ushort4*)dst)[i] = o;
}

__global__ void __launch_bounds__(256) prep_zero(unsigned short* h1buf,
                                                 unsigned short* h2buf,
                                                 int* arrive) {
  int i = blockIdx.x * blockDim.x + threadIdx.x;
  st64a((unsigned long long*)h1buf + i, 0ull);
  st64a((unsigned long long*)h1buf + 16384 + i, 0ull);
  st64a((unsigned long long*)h2buf + i, 0ull);
  st64a((unsigned long long*)h2buf + 16384 + i, 0ull);
  if (i < 256) st32a(arrive + i, 0u);
}

__global__ void __launch_bounds__(256, 1) lstm_persist(
    const unsigned short* __restrict__ x,
    const unsigned short* __restrict__ Wih1, const unsigned short* __restrict__ Whh1,
    const float* __restrict__ bih1, const float* __restrict__ bhh1,
    const unsigned short* __restrict__ Wih2, const unsigned short* __restrict__ Whh2,
    const float* __restrict__ bih2, const float* __restrict__ bhh2,
    const unsigned short* __restrict__ Wl,  const float* __restrict__ bl,
    float* __restrict__ out,
    unsigned short* __restrict__ h1buf, unsigned short* __restrict__ h2buf,
    int* __restrict__ arrive)
{
  extern __shared__ char smem[];
  unsigned short* sbuf0 = (unsigned short*)smem;
  unsigned short* sbuf1 = (unsigned short*)(smem + CHUNK_B);
  float* sG = (float*)(smem + 2 * CHUNK_B);
  float* sc = (float*)(smem + 2 * CHUNK_B + 16896);

  const int tid = threadIdx.x;
  const int bid = blockIdx.x;
  const int lane = tid & 63;
  const int wid = tid >> 6;
  const int srow = tid >> 2;          // staging row 0..63
  const int sseg = tid & 3;           // 64B segment within row

  for (int e = tid; e < 1024; e += 256) sc[e] = 0.0f;

  ACQ_FENCE();   // belt-and-braces: no stale h lines from a prior replay

  uint4 rs[4][4];                     // depth-4 relay: 64B/thread/chunk

  if (bid < NL1) {
    // =================== layer 1 ===================
    const int j0 = bid << 4;
    const int mtile = wid & 1, ntile = wid >> 1;
    const int arow = mtile * 32 + (lane & 31);
    const int brow = ntile * 32 + (lane & 31);
    const int gr = ((brow >> 4) << 10) + j0 + (brow & 15);
    const int hi8 = (lane >> 5) << 3;

    short8 w[80];
    #pragma unroll
    for (int c = 0; c < 10; ++c) {
      const unsigned short* wrow = (c < 2) ? (Wih1 + (size_t)gr * In + c * 128)
                                           : (Whh1 + (size_t)gr * Hn + (c - 2) * 128);
      #pragma unroll
      for (int k8 = 0; k8 < 8; ++k8)
        w[c * 8 + k8] = *(const short8*)(wrow + k8 * 16 + hi8);
    }
    float bs[2][2][4];
    #pragma unroll
    for (int p = 0; p < 2; ++p) {
      int pi = tid + p * 256, op = (pi & 7) << 1;
      #pragma unroll
      for (int k = 0; k < 2; ++k) {
        int o = op + k;
        #pragma unroll
        for (int g = 0; g < 4; ++g)
          bs[p][k][g] = bih1[g * 1024 + j0 + o] + bhh1[g * 1024 + j0 + o];
      }
    }

    for (int s = 0; s < Tn; ++s) {
      const int t = s;
      const unsigned short* h1rd = h1buf + ((t + 1) & 1) * BHe;
      unsigned short* h1wr = h1buf + (t & 1) * BHe;
      f32x16 acc0 = {}, acc1 = {};

      auto ldc = [&](int cc, int d) {
        const uint4* s4 = (cc < 2)
          ? (const uint4*)(x + ((size_t)srow * Tn + t) * In + cc * 128 + sseg * 32)
          : (const uint4*)(h1rd + (size_t)srow * Hn + (cc - 2) * 128 + sseg * 32);
        #pragma unroll
        for (int j = 0; j < 4; ++j) rs[d][j] = s4[j];
      };
      ldc(0, 0); ldc(1, 1); ldc(2, 2); ldc(3, 3);

      #pragma unroll
      for (int c = 0; c < 10; ++c) {
        unsigned short* buf = (c & 1) ? sbuf1 : sbuf0;
        {
          uint4* d4 = (uint4*)(buf + srow * SP + sseg * 32);
          #pragma unroll
          for (int j = 0; j < 4; ++j) d4[j] = rs[c & 3][j];
        }
        if (c + 4 < 10) ldc(c + 4, c & 3);
        RAW_BARRIER();
        const unsigned short* ab = buf + arow * SP + hi8;
        #pragma unroll
        for (int k8 = 0; k8 < 8; k8 += 2) {
          acc0 = __builtin_amdgcn_mfma_f32_32x32x16_bf16(*(const short8*)(ab + k8 * 16),      w[c * 8 + k8],     acc0, 0, 0, 0);
          acc1 = __builtin_amdgcn_mfma_f32_32x32x16_bf16(*(const short8*)(ab + k8 * 16 + 16), w[c * 8 + k8 + 1], acc1, 0, 0, 0);
        }
      }
      // one more raw barrier so last ds_reads complete before sG overwrite ordering below
      RAW_BARRIER();

      f32x16 accv = acc0 + acc1;
      #pragma unroll
      for (int i = 0; i < 16; ++i) {  // C/D: col=lane&31, row=(reg&3)+8*(reg>>2)+4*(lane>>5)
        int rm = (i & 3) + ((i >> 2) << 3) + ((lane >> 5) << 2);
        sG[(mtile * 32 + rm) * 65 + brow] = accv[i];
      }
      __syncthreads();

      #pragma unroll
      for (int p = 0; p < 2; ++p) {
        int pi = tid + p * 256;
        int b = pi >> 3, op = (pi & 7) << 1;
        const float* gb = sG + b * 65;
        unsigned int pack = 0;
        #pragma unroll
        for (int k = 0; k < 2; ++k) {
          int o = op + k, e = b * 16 + o;
          float ig = gb[o]      + bs[p][k][0];
          float fg = gb[16 + o] + bs[p][k][1];
          float gg = gb[32 + o] + bs[p][k][2];
          float og = gb[48 + o] + bs[p][k][3];
          float cn = sigm(fg) * sc[e] + sigm(ig) * tanhf_(gg);
          sc[e] = cn;
          pack |= ((unsigned int)f2b(sigm(og) * tanhf_(cn))) << (16 * k);
        }
        st32a(h1wr + b * Hn + j0 + op, pack);
      }
      grid_barrier(arrive, bid, tid, lane, s + 1);
      ACQ_FENCE();
    }
    grid_barrier(arrive, bid, tid, lane, Tn + 1);

  } else if (bid < NL1 + NL2) {
    // =================== layer 2 ===================
    const int j0 = (bid - NL1) << 3;
    const int mtile = wid & 1, ks = wid >> 1;
    const int arow = mtile * 32 + (lane & 31);
    const int brow = lane & 31;
    const int gr = ((brow >> 3) << 10) + j0 + (brow & 7);
    const int hi8 = (lane >> 5) << 3;

    short8 w[80];
    if (ks == 0) {
      #pragma unroll
      for (int c = 0; c < 10; ++c)
        #pragma unroll
        for (int k8 = 0; k8 < 8; ++k8)
          w[c * 8 + k8] = *(const short8*)(Wih2 + (size_t)gr * 1280 + c * 128 + k8 * 16 + hi8);
    } else {
      #pragma unroll
      for (int c = 0; c < 8; ++c)
        #pragma unroll
        for (int k8 = 0; k8 < 8; ++k8)
          w[c * 8 + k8] = *(const short8*)(Whh2 + (size_t)gr * Hn + c * 128 + k8 * 16 + hi8);
    }
    float bs[2][4];
    {
      int op = (tid & 3) << 1;
      #pragma unroll
      for (int k = 0; k < 2; ++k) {
        int o = op + k;
        #pragma unroll
        for (int g = 0; g < 4; ++g)
          bs[k][g] = bih2[g * 1024 + j0 + o] + bhh2[g * 1024 + j0 + o];
      }
    }

    grid_barrier(arrive, bid, tid, lane, 1);
    ACQ_FENCE();

    for (int s = 1; s <= Tn; ++s) {
      const int t = s - 1;
      const unsigned short* h1rd = h1buf + (t & 1) * BHe;        // h1(t)
      const unsigned short* h2rd = h2buf + ((t + 1) & 1) * BHe;  // h2(t-1)
      unsigned short* h2wr = h2buf + (t & 1) * BHe;              // h2(t)
      f32x16 acc0 = {}, acc1 = {};

      auto ldc = [&](int cc, int d) {
        const uint4* s4;
        if (cc < 2)       s4 = (const uint4*)(x + ((size_t)srow * Tn + t) * In + cc * 128 + sseg * 32);
        else if (cc < 10) s4 = (const uint4*)(h1rd + (size_t)srow * Hn + (cc - 2) * 128 + sseg * 32);
        else              s4 = (const uint4*)(h2rd + (size_t)srow * Hn + (cc - 10) * 128 + sseg * 32);
        #pragma unroll
        for (int j = 0; j < 4; ++j) rs[d][j] = s4[j];
      };
      ldc(0, 0); ldc(1, 1); ldc(2, 2); ldc(3, 3);

      #pragma unroll
      for (int c = 0; c < 18; ++c) {
        unsigned short* buf = (c & 1) ? sbuf1 : sbuf0;
        {
          uint4* d4 = (uint4*)(buf + srow * SP + sseg * 32);
          #pragma unroll
          for (int j = 0; j < 4; ++j) d4[j] = rs[c & 3][j];
        }
        if (c + 4 < 18) ldc(c + 4, c & 3);
        RAW_BARRIER();
        bool active = (ks == 0) ? (c < 10) : (c >= 10);
        if (active) {
          int ib = ((ks == 0) ? c : (c - 10)) * 8;
          const unsigned short* ab = buf + arow * SP + hi8;
          #pragma unroll
          for (int k8 = 0; k8 < 8; k8 += 2) {
            acc0 = __builtin_amdgcn_mfma_f32_32x32x16_bf16(*(const short8*)(ab + k8 * 16),      w[ib + k8],     acc0, 0, 0, 0);
            acc1 = __builtin_amdgcn_mfma_f32_32x32x16_bf16(*(const short8*)(ab + k8 * 16 + 16), w[ib + k8 + 1], acc1, 0, 0, 0);
          }
        }
      }
      RAW_BARRIER();

      f32x16 accv = acc0 + acc1;
      #pragma unroll
      for (int i = 0; i < 16; ++i) {
        int rm = (i & 3) + ((i >> 2) << 3) + ((lane >> 5) << 2);
        sG[ks * 2112 + (mtile * 32 + rm) * 33 + brow] = accv[i];
      }
      __syncthreads();

      {
        int b = tid >> 2, op = (tid & 3) << 1;
        const float* g0 = sG + b * 33;
        const float* g1 = sG + 2112 + b * 33;
        unsigned int pack = 0;
        #pragma unroll
        for (int k = 0; k < 2; ++k) {
          int o = op + k, e = b * 8 + o;
          float ig = g0[o]      + g1[o]      + bs[k][0];
          float fg = g0[8 + o]  + g1[8 + o]  + bs[k][1];
          float gg = g0[16 + o] + g1[16 + o] + bs[k][2];
          float og = g0[24 + o] + g1[24 + o] + bs[k][3];
          float cn = sigm(fg) * sc[e] + sigm(ig) * tanhf_(gg);
          sc[e] = cn;
          pack |= ((unsigned int)f2b(sigm(og) * tanhf_(cn))) << (16 * k);
        }
        st32a(h2wr + b * Hn + j0 + op, pack);
      }
      grid_barrier(arrive, bid, tid, lane, s + 1);
      ACQ_FENCE();
    }

  } else {
    // =================== head ===================
    const int o0 = (bid - NL1 - NL2) << 4;
    const int quad = lane >> 4;
    const int l15 = lane & 15;
    const int hi8y = quad << 3;

    short8 wy[40];
    #pragma unroll
    for (int c = 0; c < 10; ++c)
      #pragma unroll
      for (int q = 0; q < 4; ++q)
        wy[c * 4 + q] = *(const short8*)(Wl + (size_t)(o0 + l15) * 1280 + c * 128 + q * 32 + hi8y);
    const float blv = bl[o0 + l15];

    grid_barrier(arrive, bid, tid, lane, 1);
    grid_barrier(arrive, bid, tid, lane, 2);
    ACQ_FENCE();

    for (int s = 2; s <= Tn + 1; ++s) {
      const int t = s - 2;
      const unsigned short* h2rd = h2buf + (t & 1) * BHe;   // h2(t)
      f32x4 acc0 = {}, acc1 = {};

      auto ldc = [&](int cc, int d) {
        const uint4* s4 = (cc < 2)
          ? (const uint4*)(x + ((size_t)srow * Tn + t) * In + cc * 128 + sseg * 32)
          : (const uint4*)(h2rd + (size_t)srow * Hn + (cc - 2) * 128 + sseg * 32);
        #pragma unroll
        for (int j = 0; j < 4; ++j) rs[d][j] = s4[j];
      };
      ldc(0, 0); ldc(1, 1); ldc(2, 2); ldc(3, 3);

      #pragma unroll
      for (int c = 0; c < 10; ++c) {
        unsigned short* buf = (c & 1) ? sbuf1 : sbuf0;
        {
          uint4* d4 = (uint4*)(buf + srow * SP + sseg * 32);
          #pragma unroll
          for (int j = 0; j < 4; ++j) d4[j] = rs[c & 3][j];
        }
        if (c + 4 < 10) ldc(c + 4, c & 3);
        RAW_BARRIER();
        const unsigned short* ab = buf + (wid * 16 + l15) * SP + hi8y;
        acc0 = __builtin_amdgcn_mfma_f32_16x16x32_bf16(*(const short8*)(ab),      wy[c * 4 + 0], acc0, 0, 0, 0);
        acc1 = __builtin_amdgcn_mfma_f32_16x16x32_bf16(*(const short8*)(ab + 32), wy[c * 4 + 1], acc1, 0, 0, 0);
        acc0 = __builtin_amdgcn_mfma_f32_16x16x32_bf16(*(const short8*)(ab + 64), wy[c * 4 + 2], acc0, 0, 0, 0);
        acc1 = __builtin_amdgcn_mfma_f32_16x16x32_bf16(*(const short8*)(ab + 96), wy[c * 4 + 3], acc1, 0, 0, 0);
      }
      RAW_BARRIER();

      f32x4 accv = acc0 + acc1;
      #pragma unroll
      for (int i = 0; i < 4; ++i) {   // C/D 16x16: col=lane&15, row=(lane>>4)*4+reg
        int b = wid * 16 + quad * 4 + i;
        out[((size_t)b * Tn + t) * On + o0 + l15] = accv[i] + blv;
      }
      if (s <= Tn) { grid_barrier(arrive, bid, tid, lane, s + 1); ACQ_FENCE(); }
    }
  }
}

extern "C" void kernel_launch(void* const* d_in, const int* in_sizes, int n_in,
                              void* d_out, int out_size, void* d_ws, size_t ws_size,
                              hipStream_t stream) {
  (void)in_sizes; (void)n_in; (void)out_size; (void)ws_size;
  const float* xf    = (const float*)d_in[0];
  const float* Wih1f = (const float*)d_in[1];
  const float* Whh1f = (const float*)d_in[2];
  const float* bih1  = (const float*)d_in[3];
  const float* bhh1  = (const float*)d_in[4];
  const float* Wih2f = (const float*)d_in[5];
  const float* Whh2f = (const float*)d_in[6];
  const float* bih2  = (const float*)d_in[7];
  const float* bhh2  = (const float*)d_in[8];
  const float* Wlf   = (const float*)d_in[9];
  const float* bl    = (const float*)d_in[10];
  float* out = (float*)d_out;

  char* ws = (char*)d_ws;
  unsigned short* Wih1b = (unsigned short*)(ws + WS_WIH1);
  unsigned short* Whh1b = (unsigned short*)(ws + WS_WHH1);
  unsigned short* Wih2b = (unsigned short*)(ws + WS_WIH2);
  unsigned short* Whh2b = (unsigned short*)(ws + WS_WHH2);
  unsigned short* Wlb   = (unsigned short*)(ws + WS_WL);
  unsigned short* xb    = (unsigned short*)(ws + WS_X);
  unsigned short* h1buf = (unsigned short*)(ws + WS_H1);
  unsigned short* h2buf = (unsigned short*)(ws + WS_H2);
  int* arrive           = (int*)(ws + WS_ARR);

  hipLaunchKernelGGL(cvt_bf16, dim3(1024), dim3(256), 0, stream, Wih1f, Wih1b, 262144);
  hipLaunchKernelGGL(cvt_bf16, dim3(4096), dim3(256), 0, stream, Whh1f, Whh1b, 1048576);
  hipLaunchKernelGGL(cvt_bf16, dim3(5120), dim3(256), 0, stream, Wih2f, Wih2b, 1310720);
  hipLaunchKernelGGL(cvt_bf16, dim3(4096), dim3(256), 0, stream, Whh2f, Whh2b, 1048576);
  hipLaunchKernelGGL(cvt_bf16, dim3(320),  dim3(256), 0, stream, Wlf,   Wlb,   81920);
  hipLaunchKernelGGL(cvt_bf16, dim3(4096), dim3(256), 0, stream, xf,    xb,    1048576);

  hipLaunchKernelGGL(prep_zero, dim3(64), dim3(256), 0, stream, h1buf, h2buf, arrive);

  hipLaunchKernelGGL(lstm_persist, dim3(NBLK), dim3(256), SMEM_SZ, stream,
                     xb, Wih1b, Whh1b, bih1, bhh1, Wih2b, Whh2b, bih2, bhh2, Wlb, bl,
                     out, h1buf, h2buf, arrive);
}

// Round 2
// 3825.077 us; speedup vs baseline: 2.6252x; 2.6252x over previous
//
#include <hip/hip_runtime.h>

// DeepLSTM on MI355X — persistent kernel (plain launch, 208 blocks, co-resident),
// relaxed-atomic grid barrier (no cache maintenance), weights persistent in VGPR/AGPR.
// ROUND 6: K-loop software pipeline, depth-4 register relay, raw s_barrier per chunk.
// ROUND 7 (REVERTED): per-step agent acquire fence (buffer_inv) — 2x regression,
//   WRITE_SIZE x8.5: whole-L2 invalidation writes back dirty lines + refetch latency.
// ROUND 8: h relay loads changed from 8B agent-scope ATOMIC loads (not coalesced by
//   the TA -> ~5.4M individual MALL transactions/step) to plain inline-asm
//   global_load_dwordx4 with sc1 (same coherence point, 2x width, coalescable).
//   All relay loads are inline asm; manual s_waitcnt vmcnt(12/8/4/0) before each
//   chunk's LDS stage write replaces compiler vmcnt bookkeeping.

typedef __attribute__((ext_vector_type(8))) short short8;
typedef __attribute__((ext_vector_type(16))) float f32x16;
typedef __attribute__((ext_vector_type(4))) float f32x4;

#define Tn 256
#define In 256
#define Hn 1024
#define On 256
#define SP 136            // LDS act row stride (elems): 272B rows, 16B-aligned
#define NL1 64
#define NL2 128
#define NY  16
#define NBLK (NL1 + NL2 + NY)   // 208
#define CHUNK_B 17408     // 64*SP*2 bytes per LDS act chunk (128 K-cols)
#define SMEM_SZ 55808     // 2*CHUNK_B + 16896 (gate xchg) + 4096 (cell state)
#define BHe 65536

// d_ws layout
#define WS_WIH1 0
#define WS_WHH1 2097152
#define WS_WIH2 10485760
#define WS_WHH2 20971520
#define WS_WL   29360128
#define WS_X    30015488
#define WS_H1   38404096
#define WS_H2   38666240
#define WS_ARR  38928384

// s_waitcnt lgkmcnt(0), vmcnt/expcnt unconstrained (gfx9 encoding)
#define WAIT_LGKM0() __builtin_amdgcn_s_waitcnt(0xC07F)
#define RAW_BARRIER() do { \
    WAIT_LGKM0(); \
    __builtin_amdgcn_sched_barrier(0); \
    __builtin_amdgcn_s_barrier(); \
    __builtin_amdgcn_sched_barrier(0); \
  } while (0)

// Wait for relay loads: allow `rem` chunks (4 dwordx4 each) to stay in flight.
#define STAGE_WAIT(rem) do { \
    __builtin_amdgcn_sched_barrier(0); \
    if ((rem) >= 3)      asm volatile("s_waitcnt vmcnt(12)" ::: "memory"); \
    else if ((rem) == 2) asm volatile("s_waitcnt vmcnt(8)"  ::: "memory"); \
    else if ((rem) == 1) asm volatile("s_waitcnt vmcnt(4)"  ::: "memory"); \
    else                 asm volatile("s_waitcnt vmcnt(0)"  ::: "memory"); \
    __builtin_amdgcn_sched_barrier(0); \
  } while (0)

// Plain cached 16B load (x: immutable, L1/L2-cacheable)
#define GLD16(dst, ptr) \
  asm volatile("global_load_dwordx4 %0, %1, off" : "=v"(dst) : "v"(ptr))
// Agent-coherent 16B load (h: bypass L1/L2 via sc1, read from coherence point;
// same visibility as an agent-scope relaxed atomic load, but TA-coalescable)
#define GLD16C(dst, ptr) \
  asm volatile("global_load_dwordx4 %0, %1, off sc1" : "=v"(dst) : "v"(ptr))

static __device__ __forceinline__ unsigned short f2b(float f) {
  union { float f; unsigned int i; } v; v.f = f;
  unsigned int u = v.i;
  return (unsigned short)((u + 0x7FFFu + ((u >> 16) & 1u)) >> 16);  // RNE
}
static __device__ __forceinline__ float sigm(float x) { return 1.0f / (1.0f + __expf(-x)); }
static __device__ __forceinline__ float tanhf_(float x) {
  float ax = fabsf(x);
  float e = __expf(-2.0f * ax);
  return copysignf((1.0f - e) / (1.0f + e), x);
}
static __device__ __forceinline__ void st32a(void* p, unsigned int v) {
  __hip_atomic_store((unsigned int*)p, v, __ATOMIC_RELAXED, __HIP_MEMORY_SCOPE_AGENT);
}
static __device__ __forceinline__ void st64a(void* p, unsigned long long v) {
  __hip_atomic_store((unsigned long long*)p, v, __ATOMIC_RELAXED, __HIP_MEMORY_SCOPE_AGENT);
}

static __device__ __forceinline__ void grid_barrier(int* arrive, int bid, int tid,
                                                    int lane, int tgt) {
  __syncthreads();   // full drain (vmcnt0): h-stores visible before publish
  if (tid == 0)
    __hip_atomic_store(&arrive[bid], tgt, __ATOMIC_RELAXED, __HIP_MEMORY_SCOPE_AGENT);
  if (tid < 64) {
    bool done = false;
    while (!done) {
      bool ok = true;
      #pragma unroll
      for (int j = 0; j < 4; ++j) {
        int idx = lane + j * 64;
        if (idx < NBLK) {
          int v = __hip_atomic_load(&arrive[idx], __ATOMIC_RELAXED, __HIP_MEMORY_SCOPE_AGENT);
          ok = ok && (v >= tgt);
        }
      }
      done = __all(ok);
      if (!done) __builtin_amdgcn_s_sleep(1);
    }
  }
  __syncthreads();
}

__global__ void __launch_bounds__(256) cvt_bf16(const float* __restrict__ src,
                                                unsigned short* __restrict__ dst, int n4) {
  int i = blockIdx.x * blockDim.x + threadIdx.x;
  if (i >= n4) return;
  float4 v = ((const float4*)src)[i];
  ushort4 o;
  o.x = f2b(v.x); o.y = f2b(v.y); o.z = f2b(v.z); o.w = f2b(v.w);
  ((ushort4*)dst)[i] = o;
}

__global__ void __launch_bounds__(256) prep_zero(unsigned short* h1buf,
                                                 unsigned short* h2buf,
                                                 int* arrive) {
  int i = blockIdx.x * blockDim.x + threadIdx.x;
  st64a((unsigned long long*)h1buf + i, 0ull);
  st64a((unsigned long long*)h1buf + 16384 + i, 0ull);
  st64a((unsigned long long*)h2buf + i, 0ull);
  st64a((unsigned long long*)h2buf + 16384 + i, 0ull);
  if (i < 256) st32a(arrive + i, 0u);
}

__global__ void __launch_bounds__(256, 1) lstm_persist(
    const unsigned short* __restrict__ x,
    const unsigned short* __restrict__ Wih1, const unsigned short* __restrict__ Whh1,
    const float* __restrict__ bih1, const float* __restrict__ bhh1,
    const unsigned short* __restrict__ Wih2, const unsigned short* __restrict__ Whh2,
    const float* __restrict__ bih2, const float* __restrict__ bhh2,
    const unsigned short* __restrict__ Wl,  const float* __restrict__ bl,
    float* __restrict__ out,
    unsigned short* __restrict__ h1buf, unsigned short* __restrict__ h2buf,
    int* __restrict__ arrive)
{
  extern __shared__ char smem[];
  unsigned short* sbuf0 = (unsigned short*)smem;
  unsigned short* sbuf1 = (unsigned short*)(smem + CHUNK_B);
  float* sG = (float*)(smem + 2 * CHUNK_B);
  float* sc = (float*)(smem + 2 * CHUNK_B + 16896);

  const int tid = threadIdx.x;
  const int bid = blockIdx.x;
  const int lane = tid & 63;
  const int wid = tid >> 6;
  const int srow = tid >> 2;          // staging row 0..63
  const int sseg = tid & 3;           // 64B segment within row

  for (int e = tid; e < 1024; e += 256) sc[e] = 0.0f;

  uint4 rs[4][4];                     // depth-4 relay: 64B/thread/chunk

  if (bid < NL1) {
    // =================== layer 1 ===================
    const int j0 = bid << 4;
    const int mtile = wid & 1, ntile = wid >> 1;
    const int arow = mtile * 32 + (lane & 31);
    const int brow = ntile * 32 + (lane & 31);
    const int gr = ((brow >> 4) << 10) + j0 + (brow & 15);
    const int hi8 = (lane >> 5) << 3;

    short8 w[80];
    #pragma unroll
    for (int c = 0; c < 10; ++c) {
      const unsigned short* wrow = (c < 2) ? (Wih1 + (size_t)gr * In + c * 128)
                                           : (Whh1 + (size_t)gr * Hn + (c - 2) * 128);
      #pragma unroll
      for (int k8 = 0; k8 < 8; ++k8)
        w[c * 8 + k8] = *(const short8*)(wrow + k8 * 16 + hi8);
    }
    float bs[2][2][4];
    #pragma unroll
    for (int p = 0; p < 2; ++p) {
      int pi = tid + p * 256, op = (pi & 7) << 1;
      #pragma unroll
      for (int k = 0; k < 2; ++k) {
        int o = op + k;
        #pragma unroll
        for (int g = 0; g < 4; ++g)
          bs[p][k][g] = bih1[g * 1024 + j0 + o] + bhh1[g * 1024 + j0 + o];
      }
    }

    for (int s = 0; s < Tn; ++s) {
      const int t = s;
      const unsigned short* h1rd = h1buf + ((t + 1) & 1) * BHe;
      unsigned short* h1wr = h1buf + (t & 1) * BHe;
      f32x16 acc0 = {}, acc1 = {};

      auto ldc = [&](int cc, int d) {
        if (cc < 2) {
          const char* p = (const char*)(x + ((size_t)srow * Tn + t) * In + cc * 128 + sseg * 32);
          #pragma unroll
          for (int j = 0; j < 4; ++j) GLD16(rs[d][j], p + j * 16);
        } else {
          const char* p = (const char*)(h1rd + (size_t)srow * Hn + (cc - 2) * 128 + sseg * 32);
          #pragma unroll
          for (int j = 0; j < 4; ++j) GLD16C(rs[d][j], p + j * 16);
        }
      };
      ldc(0, 0); ldc(1, 1); ldc(2, 2); ldc(3, 3);

      #pragma unroll
      for (int c = 0; c < 10; ++c) {
        unsigned short* buf = (c & 1) ? sbuf1 : sbuf0;
        STAGE_WAIT(9 - c);
        {
          uint4* d4 = (uint4*)(buf + srow * SP + sseg * 32);
          #pragma unroll
          for (int j = 0; j < 4; ++j) d4[j] = rs[c & 3][j];
        }
        if (c + 4 < 10) ldc(c + 4, c & 3);
        RAW_BARRIER();
        const unsigned short* ab = buf + arow * SP + hi8;
        #pragma unroll
        for (int k8 = 0; k8 < 8; k8 += 2) {
          acc0 = __builtin_amdgcn_mfma_f32_32x32x16_bf16(*(const short8*)(ab + k8 * 16),      w[c * 8 + k8],     acc0, 0, 0, 0);
          acc1 = __builtin_amdgcn_mfma_f32_32x32x16_bf16(*(const short8*)(ab + k8 * 16 + 16), w[c * 8 + k8 + 1], acc1, 0, 0, 0);
        }
      }
      // one more raw barrier so last ds_reads complete before sG overwrite ordering below
      RAW_BARRIER();

      f32x16 accv = acc0 + acc1;
      #pragma unroll
      for (int i = 0; i < 16; ++i) {  // C/D: col=lane&31, row=(reg&3)+8*(reg>>2)+4*(lane>>5)
        int rm = (i & 3) + ((i >> 2) << 3) + ((lane >> 5) << 2);
        sG[(mtile * 32 + rm) * 65 + brow] = accv[i];
      }
      __syncthreads();

      #pragma unroll
      for (int p = 0; p < 2; ++p) {
        int pi = tid + p * 256;
        int b = pi >> 3, op = (pi & 7) << 1;
        const float* gb = sG + b * 65;
        unsigned int pack = 0;
        #pragma unroll
        for (int k = 0; k < 2; ++k) {
          int o = op + k, e = b * 16 + o;
          float ig = gb[o]      + bs[p][k][0];
          float fg = gb[16 + o] + bs[p][k][1];
          float gg = gb[32 + o] + bs[p][k][2];
          float og = gb[48 + o] + bs[p][k][3];
          float cn = sigm(fg) * sc[e] + sigm(ig) * tanhf_(gg);
          sc[e] = cn;
          pack |= ((unsigned int)f2b(sigm(og) * tanhf_(cn))) << (16 * k);
        }
        st32a(h1wr + b * Hn + j0 + op, pack);
      }
      grid_barrier(arrive, bid, tid, lane, s + 1);
    }
    grid_barrier(arrive, bid, tid, lane, Tn + 1);

  } else if (bid < NL1 + NL2) {
    // =================== layer 2 ===================
    const int j0 = (bid - NL1) << 3;
    const int mtile = wid & 1, ks = wid >> 1;
    const int arow = mtile * 32 + (lane & 31);
    const int brow = lane & 31;
    const int gr = ((brow >> 3) << 10) + j0 + (brow & 7);
    const int hi8 = (lane >> 5) << 3;

    short8 w[80];
    if (ks == 0) {
      #pragma unroll
      for (int c = 0; c < 10; ++c)
        #pragma unroll
        for (int k8 = 0; k8 < 8; ++k8)
          w[c * 8 + k8] = *(const short8*)(Wih2 + (size_t)gr * 1280 + c * 128 + k8 * 16 + hi8);
    } else {
      #pragma unroll
      for (int c = 0; c < 8; ++c)
        #pragma unroll
        for (int k8 = 0; k8 < 8; ++k8)
          w[c * 8 + k8] = *(const short8*)(Whh2 + (size_t)gr * Hn + c * 128 + k8 * 16 + hi8);
    }
    float bs[2][4];
    {
      int op = (tid & 3) << 1;
      #pragma unroll
      for (int k = 0; k < 2; ++k) {
        int o = op + k;
        #pragma unroll
        for (int g = 0; g < 4; ++g)
          bs[k][g] = bih2[g * 1024 + j0 + o] + bhh2[g * 1024 + j0 + o];
      }
    }

    grid_barrier(arrive, bid, tid, lane, 1);

    for (int s = 1; s <= Tn; ++s) {
      const int t = s - 1;
      const unsigned short* h1rd = h1buf + (t & 1) * BHe;        // h1(t)
      const unsigned short* h2rd = h2buf + ((t + 1) & 1) * BHe;  // h2(t-1)
      unsigned short* h2wr = h2buf + (t & 1) * BHe;              // h2(t)
      f32x16 acc0 = {}, acc1 = {};

      auto ldc = [&](int cc, int d) {
        if (cc < 2) {
          const char* p = (const char*)(x + ((size_t)srow * Tn + t) * In + cc * 128 + sseg * 32);
          #pragma unroll
          for (int j = 0; j < 4; ++j) GLD16(rs[d][j], p + j * 16);
        } else {
          const unsigned short* src = (cc < 10) ? (h1rd + (size_t)srow * Hn + (cc - 2) * 128)
                                                : (h2rd + (size_t)srow * Hn + (cc - 10) * 128);
          const char* p = (const char*)(src + sseg * 32);
          #pragma unroll
          for (int j = 0; j < 4; ++j) GLD16C(rs[d][j], p + j * 16);
        }
      };
      ldc(0, 0); ldc(1, 1); ldc(2, 2); ldc(3, 3);

      #pragma unroll
      for (int c = 0; c < 18; ++c) {
        unsigned short* buf = (c & 1) ? sbuf1 : sbuf0;
        STAGE_WAIT(17 - c);
        {
          uint4* d4 = (uint4*)(buf + srow * SP + sseg * 32);
          #pragma unroll
          for (int j = 0; j < 4; ++j) d4[j] = rs[c & 3][j];
        }
        if (c + 4 < 18) ldc(c + 4, c & 3);
        RAW_BARRIER();
        bool active = (ks == 0) ? (c < 10) : (c >= 10);
        if (active) {
          int ib = ((ks == 0) ? c : (c - 10)) * 8;
          const unsigned short* ab = buf + arow * SP + hi8;
          #pragma unroll
          for (int k8 = 0; k8 < 8; k8 += 2) {
            acc0 = __builtin_amdgcn_mfma_f32_32x32x16_bf16(*(const short8*)(ab + k8 * 16),      w[ib + k8],     acc0, 0, 0, 0);
            acc1 = __builtin_amdgcn_mfma_f32_32x32x16_bf16(*(const short8*)(ab + k8 * 16 + 16), w[ib + k8 + 1], acc1, 0, 0, 0);
          }
        }
      }
      RAW_BARRIER();

      f32x16 accv = acc0 + acc1;
      #pragma unroll
      for (int i = 0; i < 16; ++i) {
        int rm = (i & 3) + ((i >> 2) << 3) + ((lane >> 5) << 2);
        sG[ks * 2112 + (mtile * 32 + rm) * 33 + brow] = accv[i];
      }
      __syncthreads();

      {
        int b = tid >> 2, op = (tid & 3) << 1;
        const float* g0 = sG + b * 33;
        const float* g1 = sG + 2112 + b * 33;
        unsigned int pack = 0;
        #pragma unroll
        for (int k = 0; k < 2; ++k) {
          int o = op + k, e = b * 8 + o;
          float ig = g0[o]      + g1[o]      + bs[k][0];
          float fg = g0[8 + o]  + g1[8 + o]  + bs[k][1];
          float gg = g0[16 + o] + g1[16 + o] + bs[k][2];
          float og = g0[24 + o] + g1[24 + o] + bs[k][3];
          float cn = sigm(fg) * sc[e] + sigm(ig) * tanhf_(gg);
          sc[e] = cn;
          pack |= ((unsigned int)f2b(sigm(og) * tanhf_(cn))) << (16 * k);
        }
        st32a(h2wr + b * Hn + j0 + op, pack);
      }
      grid_barrier(arrive, bid, tid, lane, s + 1);
    }

  } else {
    // =================== head ===================
    const int o0 = (bid - NL1 - NL2) << 4;
    const int quad = lane >> 4;
    const int l15 = lane & 15;
    const int hi8y = quad << 3;

    short8 wy[40];
    #pragma unroll
    for (int c = 0; c < 10; ++c)
      #pragma unroll
      for (int q = 0; q < 4; ++q)
        wy[c * 4 + q] = *(const short8*)(Wl + (size_t)(o0 + l15) * 1280 + c * 128 + q * 32 + hi8y);
    const float blv = bl[o0 + l15];

    grid_barrier(arrive, bid, tid, lane, 1);
    grid_barrier(arrive, bid, tid, lane, 2);

    for (int s = 2; s <= Tn + 1; ++s) {
      const int t = s - 2;
      const unsigned short* h2rd = h2buf + (t & 1) * BHe;   // h2(t)
      f32x4 acc0 = {}, acc1 = {};

      auto ldc = [&](int cc, int d) {
        if (cc < 2) {
          const char* p = (const char*)(x + ((size_t)srow * Tn + t) * In + cc * 128 + sseg * 32);
          #pragma unroll
          for (int j = 0; j < 4; ++j) GLD16(rs[d][j], p + j * 16);
        } else {
          const char* p = (const char*)(h2rd + (size_t)srow * Hn + (cc - 2) * 128 + sseg * 32);
          #pragma unroll
          for (int j = 0; j < 4; ++j) GLD16C(rs[d][j], p + j * 16);
        }
      };
      ldc(0, 0); ldc(1, 1); ldc(2, 2); ldc(3, 3);

      #pragma unroll
      for (int c = 0; c < 10; ++c) {
        unsigned short* buf = (c & 1) ? sbuf1 : sbuf0;
        STAGE_WAIT(9 - c);
        {
          uint4* d4 = (uint4*)(buf + srow * SP + sseg * 32);
          #pragma unroll
          for (int j = 0; j < 4; ++j) d4[j] = rs[c & 3][j];
        }
        if (c + 4 < 10) ldc(c + 4, c & 3);
        RAW_BARRIER();
        const unsigned short* ab = buf + (wid * 16 + l15) * SP + hi8y;
        acc0 = __builtin_amdgcn_mfma_f32_16x16x32_bf16(*(const short8*)(ab),      wy[c * 4 + 0], acc0, 0, 0, 0);
        acc1 = __builtin_amdgcn_mfma_f32_16x16x32_bf16(*(const short8*)(ab + 32), wy[c * 4 + 1], acc1, 0, 0, 0);
        acc0 = __builtin_amdgcn_mfma_f32_16x16x32_bf16(*(const short8*)(ab + 64), wy[c * 4 + 2], acc0, 0, 0, 0);
        acc1 = __builtin_amdgcn_mfma_f32_16x16x32_bf16(*(const short8*)(ab + 96), wy[c * 4 + 3], acc1, 0, 0, 0);
      }
      RAW_BARRIER();

      f32x4 accv = acc0 + acc1;
      #pragma unroll
      for (int i = 0; i < 4; ++i) {   // C/D 16x16: col=lane&15, row=(lane>>4)*4+reg
        int b = wid * 16 + quad * 4 + i;
        out[((size_t)b * Tn + t) * On + o0 + l15] = accv[i] + blv;
      }
      if (s <= Tn) grid_barrier(arrive, bid, tid, lane, s + 1);
    }
  }
}

extern "C" void kernel_launch(void* const* d_in, const int* in_sizes, int n_in,
                              void* d_out, int out_size, void* d_ws, size_t ws_size,
                              hipStream_t stream) {
  (void)in_sizes; (void)n_in; (void)out_size; (void)ws_size;
  const float* xf    = (const float*)d_in[0];
  const float* Wih1f = (const float*)d_in[1];
  const float* Whh1f = (const float*)d_in[2];
  const float* bih1  = (const float*)d_in[3];
  const float* bhh1  = (const float*)d_in[4];
  const float* Wih2f = (const float*)d_in[5];
  const float* Whh2f = (const float*)d_in[6];
  const float* bih2  = (const float*)d_in[7];
  const float* bhh2  = (const float*)d_in[8];
  const float* Wlf   = (const float*)d_in[9];
  const float* bl    = (const float*)d_in[10];
  float* out = (float*)d_out;

  char* ws = (char*)d_ws;
  unsigned short* Wih1b = (unsigned short*)(ws + WS_WIH1);
  unsigned short* Whh1b = (unsigned short*)(ws + WS_WHH1);
  unsigned short* Wih2b = (unsigned short*)(ws + WS_WIH2);
  unsigned short* Whh2b = (unsigned short*)(ws + WS_WHH2);
  unsigned short* Wlb   = (unsigned short*)(ws + WS_WL);
  unsigned short* xb    = (unsigned short*)(ws + WS_X);
  unsigned short* h1buf = (unsigned short*)(ws + WS_H1);
  unsigned short* h2buf = (unsigned short*)(ws + WS_H2);
  int* arrive           = (int*)(ws + WS_ARR);

  hipLaunchKernelGGL(cvt_bf16, dim3(1024), dim3(256), 0, stream, Wih1f, Wih1b, 262144);
  hipLaunchKernelGGL(cvt_bf16, dim3(4096), dim3(256), 0, stream, Whh1f, Whh1b, 1048576);
  hipLaunchKernelGGL(cvt_bf16, dim3(5120), dim3(256), 0, stream, Wih2f, Wih2b, 1310720);
  hipLaunchKernelGGL(cvt_bf16, dim3(4096), dim3(256), 0, stream, Whh2f, Whh2b, 1048576);
  hipLaunchKernelGGL(cvt_bf16, dim3(320),  dim3(256), 0, stream, Wlf,   Wlb,   81920);
  hipLaunchKernelGGL(cvt_bf16, dim3(4096), dim3(256), 0, stream, xf,    xb,    1048576);

  hipLaunchKernelGGL(prep_zero, dim3(64), dim3(256), 0, stream, h1buf, h2buf, arrive);

  hipLaunchKernelGGL(lstm_persist, dim3(NBLK), dim3(256), SMEM_SZ, stream,
                     xb, Wih1b, Whh1b, bih1, bhh1, Wih2b, Whh2b, bih2, bhh2, Wlb, bl,
                     out, h1buf, h2buf, arrive);
}

// Round 3
// 2831.217 us; speedup vs baseline: 3.5467x; 1.3510x over previous
//
#include <hip/hip_runtime.h>

// DeepLSTM on MI355X — persistent kernel (plain launch, 208 blocks, co-resident),
// weights persistent in VGPR/AGPR.
// ROUND 6: K-loop software pipeline, depth-4 register relay, raw s_barrier per chunk.
// ROUND 7 (REVERTED): per-step agent acquire fence — 2x regression (L2-wide writeback).
// ROUND 8: h relay loads = inline-asm global_load_dwordx4 sc1 (coalescable, MALL-coherent)
//   + manual vmcnt(12/8/4/0) pipeline waits. 5244 -> 3825 us.
// ROUND 9: grid barrier restructured from all-blocks-poll-all-flags (208 blocks x 256
//   uncoalesced 4B MALL transactions per sweep on 13 lines -> ~6x slice oversubscription,
//   multi-us release propagation + contention with h prefetch) to centralized two-phase:
//   block 0 wave 0 sweeps the 208 arrival flags and publishes a single release flag
//   (own cache line, idx 240); all other blocks poll that one flag with ONE lane.

typedef __attribute__((ext_vector_type(8))) short short8;
typedef __attribute__((ext_vector_type(16))) float f32x16;
typedef __attribute__((ext_vector_type(4))) float f32x4;

#define Tn 256
#define In 256
#define Hn 1024
#define On 256
#define SP 136            // LDS act row stride (elems): 272B rows, 16B-aligned
#define NL1 64
#define NL2 128
#define NY  16
#define NBLK (NL1 + NL2 + NY)   // 208
#define CHUNK_B 17408     // 64*SP*2 bytes per LDS act chunk (128 K-cols)
#define SMEM_SZ 55808     // 2*CHUNK_B + 16896 (gate xchg) + 4096 (cell state)
#define BHe 65536
#define RELEASE_IDX 240   // release flag: own 64B line (arrival flags occupy idx 0..207)

// d_ws layout
#define WS_WIH1 0
#define WS_WHH1 2097152
#define WS_WIH2 10485760
#define WS_WHH2 20971520
#define WS_WL   29360128
#define WS_X    30015488
#define WS_H1   38404096
#define WS_H2   38666240
#define WS_ARR  38928384

// s_waitcnt lgkmcnt(0), vmcnt/expcnt unconstrained (gfx9 encoding)
#define WAIT_LGKM0() __builtin_amdgcn_s_waitcnt(0xC07F)
#define RAW_BARRIER() do { \
    WAIT_LGKM0(); \
    __builtin_amdgcn_sched_barrier(0); \
    __builtin_amdgcn_s_barrier(); \
    __builtin_amdgcn_sched_barrier(0); \
  } while (0)

// Wait for relay loads: allow `rem` chunks (4 dwordx4 each) to stay in flight.
#define STAGE_WAIT(rem) do { \
    __builtin_amdgcn_sched_barrier(0); \
    if ((rem) >= 3)      asm volatile("s_waitcnt vmcnt(12)" ::: "memory"); \
    else if ((rem) == 2) asm volatile("s_waitcnt vmcnt(8)"  ::: "memory"); \
    else if ((rem) == 1) asm volatile("s_waitcnt vmcnt(4)"  ::: "memory"); \
    else                 asm volatile("s_waitcnt vmcnt(0)"  ::: "memory"); \
    __builtin_amdgcn_sched_barrier(0); \
  } while (0)

// Plain cached 16B load (x: immutable, L1/L2-cacheable)
#define GLD16(dst, ptr) \
  asm volatile("global_load_dwordx4 %0, %1, off" : "=v"(dst) : "v"(ptr))
// Agent-coherent 16B load (h: bypass L1/L2 via sc1, read from coherence point;
// same visibility as an agent-scope relaxed atomic load, but TA-coalescable)
#define GLD16C(dst, ptr) \
  asm volatile("global_load_dwordx4 %0, %1, off sc1" : "=v"(dst) : "v"(ptr))

static __device__ __forceinline__ unsigned short f2b(float f) {
  union { float f; unsigned int i; } v; v.f = f;
  unsigned int u = v.i;
  return (unsigned short)((u + 0x7FFFu + ((u >> 16) & 1u)) >> 16);  // RNE
}
static __device__ __forceinline__ float sigm(float x) { return 1.0f / (1.0f + __expf(-x)); }
static __device__ __forceinline__ float tanhf_(float x) {
  float ax = fabsf(x);
  float e = __expf(-2.0f * ax);
  return copysignf((1.0f - e) / (1.0f + e), x);
}
static __device__ __forceinline__ int ld32a(const void* p) {
  return __hip_atomic_load((const int*)p, __ATOMIC_RELAXED, __HIP_MEMORY_SCOPE_AGENT);
}
static __device__ __forceinline__ void st32a(void* p, unsigned int v) {
  __hip_atomic_store((unsigned int*)p, v, __ATOMIC_RELAXED, __HIP_MEMORY_SCOPE_AGENT);
}
static __device__ __forceinline__ void st64a(void* p, unsigned long long v) {
  __hip_atomic_store((unsigned long long*)p, v, __ATOMIC_RELAXED, __HIP_MEMORY_SCOPE_AGENT);
}

static __device__ __forceinline__ void grid_barrier(int* arrive, int bid, int tid,
                                                    int lane, int tgt) {
  __syncthreads();   // full drain (vmcnt0): h-stores visible before publish
  if (tid == 0)
    st32a(&arrive[bid], (unsigned int)tgt);
  if (bid == 0) {
    // master: wave 0 sweeps all arrival flags, then publishes release
    if (tid < 64) {
      bool done = false;
      while (!done) {
        bool ok = true;
        #pragma unroll
        for (int j = 0; j < 4; ++j) {
          int idx = lane + j * 64;
          if (idx < NBLK) {
            int v = ld32a(&arrive[idx]);
            ok = ok && (v >= tgt);
          }
        }
        done = __all(ok);
        if (!done) __builtin_amdgcn_s_sleep(1);
      }
      if (tid == 0)
        st32a(&arrive[RELEASE_IDX], (unsigned int)tgt);
    }
    __syncthreads();
  } else {
    // followers: one lane polls the single release line
    if (tid == 0) {
      while (ld32a(&arrive[RELEASE_IDX]) < tgt) __builtin_amdgcn_s_sleep(1);
    }
    __syncthreads();
  }
}

__global__ void __launch_bounds__(256) cvt_bf16(const float* __restrict__ src,
                                                unsigned short* __restrict__ dst, int n4) {
  int i = blockIdx.x * blockDim.x + threadIdx.x;
  if (i >= n4) return;
  float4 v = ((const float4*)src)[i];
  ushort4 o;
  o.x = f2b(v.x); o.y = f2b(v.y); o.z = f2b(v.z); o.w = f2b(v.w);
  ((ushort4*)dst)[i] = o;
}

__global__ void __launch_bounds__(256) prep_zero(unsigned short* h1buf,
                                                 unsigned short* h2buf,
                                                 int* arrive) {
  int i = blockIdx.x * blockDim.x + threadIdx.x;
  st64a((unsigned long long*)h1buf + i, 0ull);
  st64a((unsigned long long*)h1buf + 16384 + i, 0ull);
  st64a((unsigned long long*)h2buf + i, 0ull);
  st64a((unsigned long long*)h2buf + 16384 + i, 0ull);
  if (i < 256) st32a(arrive + i, 0u);
}

__global__ void __launch_bounds__(256, 1) lstm_persist(
    const unsigned short* __restrict__ x,
    const unsigned short* __restrict__ Wih1, const unsigned short* __restrict__ Whh1,
    const float* __restrict__ bih1, const float* __restrict__ bhh1,
    const unsigned short* __restrict__ Wih2, const unsigned short* __restrict__ Whh2,
    const float* __restrict__ bih2, const float* __restrict__ bhh2,
    const unsigned short* __restrict__ Wl,  const float* __restrict__ bl,
    float* __restrict__ out,
    unsigned short* __restrict__ h1buf, unsigned short* __restrict__ h2buf,
    int* __restrict__ arrive)
{
  extern __shared__ char smem[];
  unsigned short* sbuf0 = (unsigned short*)smem;
  unsigned short* sbuf1 = (unsigned short*)(smem + CHUNK_B);
  float* sG = (float*)(smem + 2 * CHUNK_B);
  float* sc = (float*)(smem + 2 * CHUNK_B + 16896);

  const int tid = threadIdx.x;
  const int bid = blockIdx.x;
  const int lane = tid & 63;
  const int wid = tid >> 6;
  const int srow = tid >> 2;          // staging row 0..63
  const int sseg = tid & 3;           // 64B segment within row

  for (int e = tid; e < 1024; e += 256) sc[e] = 0.0f;

  uint4 rs[4][4];                     // depth-4 relay: 64B/thread/chunk

  if (bid < NL1) {
    // =================== layer 1 ===================
    const int j0 = bid << 4;
    const int mtile = wid & 1, ntile = wid >> 1;
    const int arow = mtile * 32 + (lane & 31);
    const int brow = ntile * 32 + (lane & 31);
    const int gr = ((brow >> 4) << 10) + j0 + (brow & 15);
    const int hi8 = (lane >> 5) << 3;

    short8 w[80];
    #pragma unroll
    for (int c = 0; c < 10; ++c) {
      const unsigned short* wrow = (c < 2) ? (Wih1 + (size_t)gr * In + c * 128)
                                           : (Whh1 + (size_t)gr * Hn + (c - 2) * 128);
      #pragma unroll
      for (int k8 = 0; k8 < 8; ++k8)
        w[c * 8 + k8] = *(const short8*)(wrow + k8 * 16 + hi8);
    }
    float bs[2][2][4];
    #pragma unroll
    for (int p = 0; p < 2; ++p) {
      int pi = tid + p * 256, op = (pi & 7) << 1;
      #pragma unroll
      for (int k = 0; k < 2; ++k) {
        int o = op + k;
        #pragma unroll
        for (int g = 0; g < 4; ++g)
          bs[p][k][g] = bih1[g * 1024 + j0 + o] + bhh1[g * 1024 + j0 + o];
      }
    }

    for (int s = 0; s < Tn; ++s) {
      const int t = s;
      const unsigned short* h1rd = h1buf + ((t + 1) & 1) * BHe;
      unsigned short* h1wr = h1buf + (t & 1) * BHe;
      f32x16 acc0 = {}, acc1 = {};

      auto ldc = [&](int cc, int d) {
        if (cc < 2) {
          const char* p = (const char*)(x + ((size_t)srow * Tn + t) * In + cc * 128 + sseg * 32);
          #pragma unroll
          for (int j = 0; j < 4; ++j) GLD16(rs[d][j], p + j * 16);
        } else {
          const char* p = (const char*)(h1rd + (size_t)srow * Hn + (cc - 2) * 128 + sseg * 32);
          #pragma unroll
          for (int j = 0; j < 4; ++j) GLD16C(rs[d][j], p + j * 16);
        }
      };
      ldc(0, 0); ldc(1, 1); ldc(2, 2); ldc(3, 3);

      #pragma unroll
      for (int c = 0; c < 10; ++c) {
        unsigned short* buf = (c & 1) ? sbuf1 : sbuf0;
        STAGE_WAIT(9 - c);
        {
          uint4* d4 = (uint4*)(buf + srow * SP + sseg * 32);
          #pragma unroll
          for (int j = 0; j < 4; ++j) d4[j] = rs[c & 3][j];
        }
        if (c + 4 < 10) ldc(c + 4, c & 3);
        RAW_BARRIER();
        const unsigned short* ab = buf + arow * SP + hi8;
        #pragma unroll
        for (int k8 = 0; k8 < 8; k8 += 2) {
          acc0 = __builtin_amdgcn_mfma_f32_32x32x16_bf16(*(const short8*)(ab + k8 * 16),      w[c * 8 + k8],     acc0, 0, 0, 0);
          acc1 = __builtin_amdgcn_mfma_f32_32x32x16_bf16(*(const short8*)(ab + k8 * 16 + 16), w[c * 8 + k8 + 1], acc1, 0, 0, 0);
        }
      }
      // one more raw barrier so last ds_reads complete before sG overwrite ordering below
      RAW_BARRIER();

      f32x16 accv = acc0 + acc1;
      #pragma unroll
      for (int i = 0; i < 16; ++i) {  // C/D: col=lane&31, row=(reg&3)+8*(reg>>2)+4*(lane>>5)
        int rm = (i & 3) + ((i >> 2) << 3) + ((lane >> 5) << 2);
        sG[(mtile * 32 + rm) * 65 + brow] = accv[i];
      }
      __syncthreads();

      #pragma unroll
      for (int p = 0; p < 2; ++p) {
        int pi = tid + p * 256;
        int b = pi >> 3, op = (pi & 7) << 1;
        const float* gb = sG + b * 65;
        unsigned int pack = 0;
        #pragma unroll
        for (int k = 0; k < 2; ++k) {
          int o = op + k, e = b * 16 + o;
          float ig = gb[o]      + bs[p][k][0];
          float fg = gb[16 + o] + bs[p][k][1];
          float gg = gb[32 + o] + bs[p][k][2];
          float og = gb[48 + o] + bs[p][k][3];
          float cn = sigm(fg) * sc[e] + sigm(ig) * tanhf_(gg);
          sc[e] = cn;
          pack |= ((unsigned int)f2b(sigm(og) * tanhf_(cn))) << (16 * k);
        }
        st32a(h1wr + b * Hn + j0 + op, pack);
      }
      grid_barrier(arrive, bid, tid, lane, s + 1);
    }
    grid_barrier(arrive, bid, tid, lane, Tn + 1);

  } else if (bid < NL1 + NL2) {
    // =================== layer 2 ===================
    const int j0 = (bid - NL1) << 3;
    const int mtile = wid & 1, ks = wid >> 1;
    const int arow = mtile * 32 + (lane & 31);
    const int brow = lane & 31;
    const int gr = ((brow >> 3) << 10) + j0 + (brow & 7);
    const int hi8 = (lane >> 5) << 3;

    short8 w[80];
    if (ks == 0) {
      #pragma unroll
      for (int c = 0; c < 10; ++c)
        #pragma unroll
        for (int k8 = 0; k8 < 8; ++k8)
          w[c * 8 + k8] = *(const short8*)(Wih2 + (size_t)gr * 1280 + c * 128 + k8 * 16 + hi8);
    } else {
      #pragma unroll
      for (int c = 0; c < 8; ++c)
        #pragma unroll
        for (int k8 = 0; k8 < 8; ++k8)
          w[c * 8 + k8] = *(const short8*)(Whh2 + (size_t)gr * Hn + c * 128 + k8 * 16 + hi8);
    }
    float bs[2][4];
    {
      int op = (tid & 3) << 1;
      #pragma unroll
      for (int k = 0; k < 2; ++k) {
        int o = op + k;
        #pragma unroll
        for (int g = 0; g < 4; ++g)
          bs[k][g] = bih2[g * 1024 + j0 + o] + bhh2[g * 1024 + j0 + o];
      }
    }

    grid_barrier(arrive, bid, tid, lane, 1);

    for (int s = 1; s <= Tn; ++s) {
      const int t = s - 1;
      const unsigned short* h1rd = h1buf + (t & 1) * BHe;        // h1(t)
      const unsigned short* h2rd = h2buf + ((t + 1) & 1) * BHe;  // h2(t-1)
      unsigned short* h2wr = h2buf + (t & 1) * BHe;              // h2(t)
      f32x16 acc0 = {}, acc1 = {};

      auto ldc = [&](int cc, int d) {
        if (cc < 2) {
          const char* p = (const char*)(x + ((size_t)srow * Tn + t) * In + cc * 128 + sseg * 32);
          #pragma unroll
          for (int j = 0; j < 4; ++j) GLD16(rs[d][j], p + j * 16);
        } else {
          const unsigned short* src = (cc < 10) ? (h1rd + (size_t)srow * Hn + (cc - 2) * 128)
                                                : (h2rd + (size_t)srow * Hn + (cc - 10) * 128);
          const char* p = (const char*)(src + sseg * 32);
          #pragma unroll
          for (int j = 0; j < 4; ++j) GLD16C(rs[d][j], p + j * 16);
        }
      };
      ldc(0, 0); ldc(1, 1); ldc(2, 2); ldc(3, 3);

      #pragma unroll
      for (int c = 0; c < 18; ++c) {
        unsigned short* buf = (c & 1) ? sbuf1 : sbuf0;
        STAGE_WAIT(17 - c);
        {
          uint4* d4 = (uint4*)(buf + srow * SP + sseg * 32);
          #pragma unroll
          for (int j = 0; j < 4; ++j) d4[j] = rs[c & 3][j];
        }
        if (c + 4 < 18) ldc(c + 4, c & 3);
        RAW_BARRIER();
        bool active = (ks == 0) ? (c < 10) : (c >= 10);
        if (active) {
          int ib = ((ks == 0) ? c : (c - 10)) * 8;
          const unsigned short* ab = buf + arow * SP + hi8;
          #pragma unroll
          for (int k8 = 0; k8 < 8; k8 += 2) {
            acc0 = __builtin_amdgcn_mfma_f32_32x32x16_bf16(*(const short8*)(ab + k8 * 16),      w[ib + k8],     acc0, 0, 0, 0);
            acc1 = __builtin_amdgcn_mfma_f32_32x32x16_bf16(*(const short8*)(ab + k8 * 16 + 16), w[ib + k8 + 1], acc1, 0, 0, 0);
          }
        }
      }
      RAW_BARRIER();

      f32x16 accv = acc0 + acc1;
      #pragma unroll
      for (int i = 0; i < 16; ++i) {
        int rm = (i & 3) + ((i >> 2) << 3) + ((lane >> 5) << 2);
        sG[ks * 2112 + (mtile * 32 + rm) * 33 + brow] = accv[i];
      }
      __syncthreads();

      {
        int b = tid >> 2, op = (tid & 3) << 1;
        const float* g0 = sG + b * 33;
        const float* g1 = sG + 2112 + b * 33;
        unsigned int pack = 0;
        #pragma unroll
        for (int k = 0; k < 2; ++k) {
          int o = op + k, e = b * 8 + o;
          float ig = g0[o]      + g1[o]      + bs[k][0];
          float fg = g0[8 + o]  + g1[8 + o]  + bs[k][1];
          float gg = g0[16 + o] + g1[16 + o] + bs[k][2];
          float og = g0[24 + o] + g1[24 + o] + bs[k][3];
          float cn = sigm(fg) * sc[e] + sigm(ig) * tanhf_(gg);
          sc[e] = cn;
          pack |= ((unsigned int)f2b(sigm(og) * tanhf_(cn))) << (16 * k);
        }
        st32a(h2wr + b * Hn + j0 + op, pack);
      }
      grid_barrier(arrive, bid, tid, lane, s + 1);
    }

  } else {
    // =================== head ===================
    const int o0 = (bid - NL1 - NL2) << 4;
    const int quad = lane >> 4;
    const int l15 = lane & 15;
    const int hi8y = quad << 3;

    short8 wy[40];
    #pragma unroll
    for (int c = 0; c < 10; ++c)
      #pragma unroll
      for (int q = 0; q < 4; ++q)
        wy[c * 4 + q] = *(const short8*)(Wl + (size_t)(o0 + l15) * 1280 + c * 128 + q * 32 + hi8y);
    const float blv = bl[o0 + l15];

    grid_barrier(arrive, bid, tid, lane, 1);
    grid_barrier(arrive, bid, tid, lane, 2);

    for (int s = 2; s <= Tn + 1; ++s) {
      const int t = s - 2;
      const unsigned short* h2rd = h2buf + (t & 1) * BHe;   // h2(t)
      f32x4 acc0 = {}, acc1 = {};

      auto ldc = [&](int cc, int d) {
        if (cc < 2) {
          const char* p = (const char*)(x + ((size_t)srow * Tn + t) * In + cc * 128 + sseg * 32);
          #pragma unroll
          for (int j = 0; j < 4; ++j) GLD16(rs[d][j], p + j * 16);
        } else {
          const char* p = (const char*)(h2rd + (size_t)srow * Hn + (cc - 2) * 128 + sseg * 32);
          #pragma unroll
          for (int j = 0; j < 4; ++j) GLD16C(rs[d][j], p + j * 16);
        }
      };
      ldc(0, 0); ldc(1, 1); ldc(2, 2); ldc(3, 3);

      #pragma unroll
      for (int c = 0; c < 10; ++c) {
        unsigned short* buf = (c & 1) ? sbuf1 : sbuf0;
        STAGE_WAIT(9 - c);
        {
          uint4* d4 = (uint4*)(buf + srow * SP + sseg * 32);
          #pragma unroll
          for (int j = 0; j < 4; ++j) d4[j] = rs[c & 3][j];
        }
        if (c + 4 < 10) ldc(c + 4, c & 3);
        RAW_BARRIER();
        const unsigned short* ab = buf + (wid * 16 + l15) * SP + hi8y;
        acc0 = __builtin_amdgcn_mfma_f32_16x16x32_bf16(*(const short8*)(ab),      wy[c * 4 + 0], acc0, 0, 0, 0);
        acc1 = __builtin_amdgcn_mfma_f32_16x16x32_bf16(*(const short8*)(ab + 32), wy[c * 4 + 1], acc1, 0, 0, 0);
        acc0 = __builtin_amdgcn_mfma_f32_16x16x32_bf16(*(const short8*)(ab + 64), wy[c * 4 + 2], acc0, 0, 0, 0);
        acc1 = __builtin_amdgcn_mfma_f32_16x16x32_bf16(*(const short8*)(ab + 96), wy[c * 4 + 3], acc1, 0, 0, 0);
      }
      RAW_BARRIER();

      f32x4 accv = acc0 + acc1;
      #pragma unroll
      for (int i = 0; i < 4; ++i) {   // C/D 16x16: col=lane&15, row=(lane>>4)*4+reg
        int b = wid * 16 + quad * 4 + i;
        out[((size_t)b * Tn + t) * On + o0 + l15] = accv[i] + blv;
      }
      if (s <= Tn) grid_barrier(arrive, bid, tid, lane, s + 1);
    }
  }
}

extern "C" void kernel_launch(void* const* d_in, const int* in_sizes, int n_in,
                              void* d_out, int out_size, void* d_ws, size_t ws_size,
                              hipStream_t stream) {
  (void)in_sizes; (void)n_in; (void)out_size; (void)ws_size;
  const float* xf    = (const float*)d_in[0];
  const float* Wih1f = (const float*)d_in[1];
  const float* Whh1f = (const float*)d_in[2];
  const float* bih1  = (const float*)d_in[3];
  const float* bhh1  = (const float*)d_in[4];
  const float* Wih2f = (const float*)d_in[5];
  const float* Whh2f = (const float*)d_in[6];
  const float* bih2  = (const float*)d_in[7];
  const float* bhh2  = (const float*)d_in[8];
  const float* Wlf   = (const float*)d_in[9];
  const float* bl    = (const float*)d_in[10];
  float* out = (float*)d_out;

  char* ws = (char*)d_ws;
  unsigned short* Wih1b = (unsigned short*)(ws + WS_WIH1);
  unsigned short* Whh1b = (unsigned short*)(ws + WS_WHH1);
  unsigned short* Wih2b = (unsigned short*)(ws + WS_WIH2);
  unsigned short* Whh2b = (unsigned short*)(ws + WS_WHH2);
  unsigned short* Wlb   = (unsigned short*)(ws + WS_WL);
  unsigned short* xb    = (unsigned short*)(ws + WS_X);
  unsigned short* h1buf = (unsigned short*)(ws + WS_H1);
  unsigned short* h2buf = (unsigned short*)(ws + WS_H2);
  int* arrive           = (int*)(ws + WS_ARR);

  hipLaunchKernelGGL(cvt_bf16, dim3(1024), dim3(256), 0, stream, Wih1f, Wih1b, 262144);
  hipLaunchKernelGGL(cvt_bf16, dim3(4096), dim3(256), 0, stream, Whh1f, Whh1b, 1048576);
  hipLaunchKernelGGL(cvt_bf16, dim3(5120), dim3(256), 0, stream, Wih2f, Wih2b, 1310720);
  hipLaunchKernelGGL(cvt_bf16, dim3(4096), dim3(256), 0, stream, Whh2f, Whh2b, 1048576);
  hipLaunchKernelGGL(cvt_bf16, dim3(320),  dim3(256), 0, stream, Wlf,   Wlb,   81920);
  hipLaunchKernelGGL(cvt_bf16, dim3(4096), dim3(256), 0, stream, xf,    xb,    1048576);

  hipLaunchKernelGGL(prep_zero, dim3(64), dim3(256), 0, stream, h1buf, h2buf, arrive);

  hipLaunchKernelGGL(lstm_persist, dim3(NBLK), dim3(256), SMEM_SZ, stream,
                     xb, Wih1b, Whh1b, bih1, bhh1, Wih2b, Whh2b, bih2, bhh2, Wlb, bl,
                     out, h1buf, h2buf, arrive);
}